// Round 1
// baseline (998.532 us; speedup 1.0000x reference)
//
#include <hip/hip_runtime.h>
#include <math.h>

// Problem constants (fixed by setup_inputs)
constexpr int Bsz   = 8;
constexpr int Cch   = 32;
constexpr int WIMG  = 128;
constexpr int OH    = 64;     // ceil(128/2)
constexpr int OW    = 64;
constexpr int INCH  = 201;    // K*C*2 + K*K
constexpr int INCHP = 204;    // padded to multiple of 4 (16B rows)
constexpr int OUTCH = 1152;   // C*NEW*NEW*K*K
constexpr float BN_EPS = 1e-5f;

// ---------------------------------------------------------------------------
// Prep: fold BN scale into conv weights, pad rows 201 -> 204 (16B aligned),
// compute fused bias. Runs every call (ws is re-poisoned before each launch).
// ---------------------------------------------------------------------------
__global__ void prep_kernel(const float* __restrict__ conv_w,
                            const float* __restrict__ gamma,
                            const float* __restrict__ beta,
                            const float* __restrict__ mean,
                            const float* __restrict__ var,
                            float* __restrict__ Wp,
                            float* __restrict__ biasp) {
    int idx = blockIdx.x * blockDim.x + threadIdx.x;
    const int nW = OUTCH * INCHP;
    if (idx < nW) {
        int o = idx / INCHP;
        int f = idx - o * INCHP;
        float inv = gamma[o] * rsqrtf(var[o] + BN_EPS);
        Wp[idx] = (f < INCH) ? conv_w[o * INCH + f] * inv : 0.0f;
    } else if (idx < nW + OUTCH) {
        int o = idx - nW;
        float inv = gamma[o] * rsqrtf(var[o] + BN_EPS);
        biasp[o] = beta[o] - mean[o] * inv;
    }
}

// ---------------------------------------------------------------------------
// Fused main kernel: one block per (b, ho). 512 threads = 8 waves.
//  stage 1: 3 input rows x 32 ch -> LDS (padded cols, 130 stride)
//  stage 2: feat[201] for all 64 wo -> LDS (stride 204: ds_read_b128 of
//           f-quads hits all 32 banks evenly: lane*204 mod 32 cycles
//           {0,12,24,4,16,28,8,20} -> offsets cover banks 0..31)
//  stage 3: per wave, per c: 36 dot products of length 204; weights via
//           wave-uniform scalar loads; epilogue = ReLU + dynamic-kernel mean.
// ---------------------------------------------------------------------------
__global__ __launch_bounds__(512)
void revnaive_main(const float* __restrict__ x,
                   const float* __restrict__ Wp,
                   const float* __restrict__ biasp,
                   float* __restrict__ out) {
    // sx: [c][i][130] padded cols (col 0 <-> x col -1), stride 390 per c
    __shared__ __align__(16) float sx[Cch * 3 * 130];      // 49,920 B
    // sfeat: [wo][204]
    __shared__ __align__(16) float sfeat[OW * INCHP];      // 52,224 B

    const int b  = blockIdx.x >> 6;
    const int ho = blockIdx.x & 63;
    const int t  = threadIdx.x;

    // ---- stage 1: load 3 rows (2*ho-1 .. 2*ho+1) of all 32 channels ----
    for (int idx = t; idx < Cch * 3 * 128; idx += 512) {
        int c   = idx / 384;
        int rem = idx - c * 384;
        int i   = rem >> 7;
        int col = rem & 127;
        int r   = 2 * ho - 1 + i;
        float v = 0.0f;
        if (r >= 0 && r < WIMG)
            v = x[(((size_t)(b * Cch + c) * WIMG) + r) * WIMG + col];
        sx[(c * 3 + i) * 130 + col + 1] = v;
    }
    if (t < 96) {               // zero the horizontal pads
        sx[t * 130]       = 0.0f;
        sx[t * 130 + 129] = 0.0f;
    }
    __syncthreads();

    // ---- stage 2: feature vector per wo ----
    const int wo = t & 63;
    for (int f = t >> 6; f < INCHP; f += 8) {   // f uniform per wave
        float m;
        if (f < 9) {                            // x1: max over channels
            int i = f / 3, j = f - 3 * i;
            int off = i * 130 + 2 * wo + j;
            m = sx[off];
            #pragma unroll
            for (int c = 1; c < Cch; ++c) m = fmaxf(m, sx[c * 390 + off]);
        } else if (f < 105) {                   // x2: max over kernel rows i
            int r = f - 9;
            int c = r / 3, j = r - 3 * c;
            int base = c * 390 + 2 * wo + j;
            m = fmaxf(fmaxf(sx[base], sx[base + 130]), sx[base + 260]);
        } else if (f < 201) {                   // x3: max over kernel cols j
            int r = f - 105;
            int c = r / 3, i = r - 3 * c;
            int base = c * 390 + i * 130 + 2 * wo;
            m = fmaxf(fmaxf(sx[base], sx[base + 1]), sx[base + 2]);
        } else {
            m = 0.0f;                           // padding features
        }
        sfeat[wo * INCHP + f] = m;
    }
    __syncthreads();

    // ---- stage 3: GEMM (36 outputs per (wo,c)) + epilogue ----
    const int wave = t >> 6;
    const float* fcol = sfeat + wo * INCHP;     // lane-varying LDS column

    for (int it = 0; it < 4; ++it) {
        const int c = wave + it * 8;            // wave-uniform in practice
        const int crow = __builtin_amdgcn_readfirstlane(c * 36);
        const float* Wc = Wp + (size_t)crow * INCHP;   // uniform -> s_load
        const float* bc = biasp + crow;                // uniform -> s_load

        float acc[36];
        #pragma unroll
        for (int s = 0; s < 36; ++s) acc[s] = 0.0f;

        for (int f0 = 0; f0 < INCHP; f0 += 4) {
            float4 v = *(const float4*)(fcol + f0);    // ds_read_b128
            #pragma unroll
            for (int s = 0; s < 36; ++s) {
                const float* wr = Wc + s * INCHP + f0; // s_load_dwordx4
                float a = acc[s];
                a = fmaf(v.x, wr[0], a);
                a = fmaf(v.y, wr[1], a);
                a = fmaf(v.z, wr[2], a);
                a = fmaf(v.w, wr[3], a);
                acc[s] = a;
            }
        }

        // epilogue: p[c][q], y = relu(acc + bias), out = mean_q(p*y)
        float p[9];
        #pragma unroll
        for (int i = 0; i < 3; ++i)
            #pragma unroll
            for (int j = 0; j < 3; ++j)
                p[i * 3 + j] = sx[c * 390 + i * 130 + 2 * wo + j];

        float o00 = 0.f, o01 = 0.f, o10 = 0.f, o11 = 0.f;
        #pragma unroll
        for (int q = 0; q < 9; ++q) {
            float pq = p[q];
            float y0 = fmaxf(acc[q * 4 + 0] + bc[q * 4 + 0], 0.0f);
            float y1 = fmaxf(acc[q * 4 + 1] + bc[q * 4 + 1], 0.0f);
            float y2 = fmaxf(acc[q * 4 + 2] + bc[q * 4 + 2], 0.0f);
            float y3 = fmaxf(acc[q * 4 + 3] + bc[q * 4 + 3], 0.0f);
            o00 = fmaf(pq, y0, o00);
            o01 = fmaf(pq, y1, o01);
            o10 = fmaf(pq, y2, o10);
            o11 = fmaf(pq, y3, o11);
        }
        const float s9 = 1.0f / 9.0f;
        float2 r0 = make_float2(o00 * s9, o01 * s9);
        float2 r1 = make_float2(o10 * s9, o11 * s9);
        size_t base = (((size_t)(b * Cch + c) * WIMG) + 2 * ho) * WIMG + 2 * wo;
        *(float2*)(out + base)        = r0;   // row 2*ho,   cols 2wo..2wo+1
        *(float2*)(out + base + WIMG) = r1;   // row 2*ho+1
    }
}

extern "C" void kernel_launch(void* const* d_in, const int* in_sizes, int n_in,
                              void* d_out, int out_size, void* d_ws, size_t ws_size,
                              hipStream_t stream) {
    const float* x      = (const float*)d_in[0];
    const float* conv_w = (const float*)d_in[1];
    const float* gamma  = (const float*)d_in[2];
    const float* beta   = (const float*)d_in[3];
    const float* mean   = (const float*)d_in[4];
    const float* var    = (const float*)d_in[5];
    float* out = (float*)d_out;

    float* Wp    = (float*)d_ws;                 // OUTCH*INCHP floats
    float* biasp = Wp + OUTCH * INCHP;           // OUTCH floats

    const int nPrep = OUTCH * INCHP + OUTCH;
    prep_kernel<<<(nPrep + 255) / 256, 256, 0, stream>>>(conv_w, gamma, beta,
                                                         mean, var, Wp, biasp);
    revnaive_main<<<Bsz * OH, 512, 0, stream>>>(x, Wp, biasp, out);
}

// Round 2
// 212.767 us; speedup vs baseline: 4.6931x; 4.6931x over previous
//
#include <hip/hip_runtime.h>
#include <math.h>

typedef __bf16 v8bf __attribute__((ext_vector_type(8)));
typedef float  v4f  __attribute__((ext_vector_type(4)));

constexpr int Bsz  = 8;
constexpr int Cch  = 32;
constexpr int WIMG = 128;
constexpr int OH   = 64;
constexpr int OW   = 64;
constexpr int INCH = 201;      // true K
constexpr int KP   = 224;      // padded K (7 chunks of 32)
constexpr int NK   = 7;
constexpr int OUTCH = 1152;
constexpr int MTOT = Bsz * OH * OW;   // 32768 spatial rows
constexpr float BN_EPS = 1e-5f;

// ---- workspace layout (bytes) ----
// Wt_t : [7][1152][32] bf16 (BN-folded W^T, k-tiled)   516,096 B
// biasp: [1152] fp32                                     4,608 B
// feat_t:[7][32768][32] bf16 (k-tiled features)     14,680,064 B
constexpr size_t WT_BYTES  = (size_t)NK * OUTCH * 32 * 2;
constexpr size_t BIAS_OFF  = WT_BYTES;                    // 516096 (16-aligned)
constexpr size_t FEAT_OFF  = BIAS_OFF + OUTCH * 4;        // 520704 (16-aligned)

// ---------------------------------------------------------------------------
// prep: BN-fold + bf16 + transpose + k-tile weights; fused bias.
// ---------------------------------------------------------------------------
__global__ void prep_kernel(const float* __restrict__ conv_w,
                            const float* __restrict__ gamma,
                            const float* __restrict__ beta,
                            const float* __restrict__ mean,
                            const float* __restrict__ var,
                            __bf16* __restrict__ Wt,
                            float* __restrict__ biasp) {
    int idx = blockIdx.x * blockDim.x + threadIdx.x;
    const int nW = OUTCH * KP;
    if (idx < nW) {
        int o = idx / KP;
        int f = idx - o * KP;
        float inv = gamma[o] * rsqrtf(var[o] + BN_EPS);
        float v = (f < INCH) ? conv_w[o * INCH + f] * inv : 0.0f;
        Wt[((size_t)(f >> 5) * OUTCH + o) * 32 + (f & 31)] = (__bf16)v;
    } else if (idx < nW + OUTCH) {
        int o = idx - nW;
        float inv = gamma[o] * rsqrtf(var[o] + BN_EPS);
        biasp[o] = beta[o] - mean[o] * inv;
    }
}

// ---------------------------------------------------------------------------
// feat: one block per (b,ho). Stage 3 input rows x 32ch into LDS, compute the
// 201 (padded 224) features per wo, write bf16 k-tiled, coalesced.
// Max-math identical to the Round-1-validated kernel.
// ---------------------------------------------------------------------------
__global__ __launch_bounds__(256)
void feat_kernel(const float* __restrict__ x, __bf16* __restrict__ feat) {
    __shared__ __align__(16) float sx[Cch * 3 * 130];
    const int b  = blockIdx.x >> 6;
    const int ho = blockIdx.x & 63;
    const int t  = threadIdx.x;

    for (int idx = t; idx < Cch * 3 * 128; idx += 256) {
        int c   = idx / 384;
        int rem = idx - c * 384;
        int i   = rem >> 7;
        int col = rem & 127;
        int r   = 2 * ho - 1 + i;
        float v = 0.0f;
        if (r >= 0 && r < WIMG)
            v = x[(((size_t)(b * Cch + c) * WIMG) + r) * WIMG + col];
        sx[(c * 3 + i) * 130 + col + 1] = v;
    }
    if (t < 96) { sx[t * 130] = 0.0f; sx[t * 130 + 129] = 0.0f; }
    __syncthreads();

    const int fl = t & 31;          // feature-within-chunk (lane-fast -> coalesced)
    const int wq = t >> 5;          // 0..7
    const size_t spat0 = (size_t)(b * OH + ho) * OW;

    for (int kc = 0; kc < NK; ++kc) {
        int f = kc * 32 + fl;
        for (int wi = 0; wi < 8; ++wi) {
            int wo = wi * 8 + wq;
            float m;
            if (f < 9) {                              // max over channels
                int i = f / 3, j = f - 3 * i;
                int off = i * 130 + 2 * wo + j;
                m = sx[off];
                #pragma unroll
                for (int c = 1; c < Cch; ++c) m = fmaxf(m, sx[c * 390 + off]);
            } else if (f < 105) {                     // max over kernel rows
                int r = f - 9;
                int c = r / 3, j = r - 3 * c;
                int base = c * 390 + 2 * wo + j;
                m = fmaxf(fmaxf(sx[base], sx[base + 130]), sx[base + 260]);
            } else if (f < 201) {                     // max over kernel cols
                int r = f - 105;
                int c = r / 3, i = r - 3 * c;
                int base = c * 390 + i * 130 + 2 * wo;
                m = fmaxf(fmaxf(sx[base], sx[base + 1]), sx[base + 2]);
            } else {
                m = 0.0f;                             // K padding
            }
            feat[((size_t)kc * MTOT + spat0 + wo) * 32 + fl] = (__bf16)m;
        }
    }
}

// ---------------------------------------------------------------------------
// gemm: MFMA bf16 16x16x32. Block = 256 thr (4 waves), tile M=256 x N=144,
// K=224 double-buffered. Wave w: M-tiles 4w..4w+3 x all 9 N-tiles ->
// 36 MFMAs per 13 ds_read_b128 per kstep. Fused BN/ReLU/dyn-kernel epilogue.
// LDS rows padded 64->80 B: within-quad banks fully spread.
// ---------------------------------------------------------------------------
__global__ __launch_bounds__(256, 2)
void gemm_kernel(const __bf16* __restrict__ feat,
                 const __bf16* __restrict__ Wt,
                 const float* __restrict__ biasp,
                 const float* __restrict__ x,
                 float* __restrict__ out) {
    __shared__ __align__(16) unsigned char lds[74240];
    // staging union:  A dbuf @0/@20480 (256 rows * 80B), B dbuf @40960/@52480 (144*80B)
    // epilogue union: y fp32 [128][145] @0 (74,240 B)

    const int t    = threadIdx.x;
    const int mb   = (int)blockIdx.x >> 3;
    const int nb   = (int)blockIdx.x & 7;
    const int M0   = mb * 256;
    const int N0   = nb * 144;
    const int wave = t >> 6, lane = t & 63, quad = lane >> 4, l16 = lane & 15;

    v4f acc[4][9];
    #pragma unroll
    for (int mt = 0; mt < 4; ++mt)
        #pragma unroll
        for (int nt = 0; nt < 9; ++nt)
            acc[mt][nt] = (v4f){0.f, 0.f, 0.f, 0.f};

    float4 ar[4], br[3];
    auto load_stage = [&](int ks) {
        const float4* Ag = (const float4*)((const char*)feat + ((size_t)ks * MTOT + M0) * 64);
        #pragma unroll
        for (int i = 0; i < 4; ++i) ar[i] = Ag[t + 256 * i];
        const float4* Bg = (const float4*)((const char*)Wt + ((size_t)ks * OUTCH + N0) * 64);
        br[0] = Bg[t];
        br[1] = Bg[t + 256];
        if (t < 64) br[2] = Bg[t + 512];
    };
    auto write_stage = [&](int buf) {
        char* Ab = (char*)lds + buf * 20480;
        #pragma unroll
        for (int i = 0; i < 4; ++i) {
            int u = t + 256 * i;
            *(float4*)(Ab + (u >> 2) * 80 + (u & 3) * 16) = ar[i];
        }
        char* Bb = (char*)lds + 40960 + buf * 11520;
        { int u = t;       *(float4*)(Bb + (u >> 2) * 80 + (u & 3) * 16) = br[0]; }
        { int u = t + 256; *(float4*)(Bb + (u >> 2) * 80 + (u & 3) * 16) = br[1]; }
        if (t < 64) { int u = t + 512; *(float4*)(Bb + (u >> 2) * 80 + (u & 3) * 16) = br[2]; }
    };

    load_stage(0);
    write_stage(0);
    __syncthreads();

    for (int ks = 0; ks < NK; ++ks) {
        const int cur = ks & 1;
        if (ks + 1 < NK) load_stage(ks + 1);   // L2 latency hides behind MFMAs

        const char* Ab = (const char*)lds + cur * 20480;
        const char* Bb = (const char*)lds + 40960 + cur * 11520;
        v8bf af[4];
        #pragma unroll
        for (int mt = 0; mt < 4; ++mt)
            af[mt] = *(const v8bf*)(Ab + (wave * 64 + mt * 16 + l16) * 80 + quad * 16);
        #pragma unroll
        for (int nt = 0; nt < 9; ++nt) {
            v8bf bf = *(const v8bf*)(Bb + (nt * 16 + l16) * 80 + quad * 16);
            #pragma unroll
            for (int mt = 0; mt < 4; ++mt)
                acc[mt][nt] = __builtin_amdgcn_mfma_f32_16x16x32_bf16(
                    af[mt], bf, acc[mt][nt], 0, 0, 0);
        }
        if (ks + 1 < NK) {
            __syncthreads();
            write_stage((ks + 1) & 1);
            __syncthreads();
        }
    }

    // ---- epilogue: per half (128 rows): acc -> y LDS (+bias, ReLU), then
    //      out[m][c][2x2] = mean_q p[q]*y, coalesced float2 stores ----
    float* y = (float*)lds;
    const int row_base = mb * 4;          // global (b*64+ho) row index base
    const int b = row_base >> 6;          // uniform over block
    const float s9 = 1.0f / 9.0f;

    for (int h = 0; h < 2; ++h) {
        __syncthreads();                  // staging/y reads of prev phase done
        if ((wave >> 1) == h) {
            int wl = wave & 1;
            #pragma unroll
            for (int nt = 0; nt < 9; ++nt) {
                float bia = biasp[N0 + nt * 16 + l16];
                #pragma unroll
                for (int mt = 0; mt < 4; ++mt) {
                    int mloc = wl * 64 + mt * 16 + quad * 4;
                    #pragma unroll
                    for (int r = 0; r < 4; ++r)
                        y[(mloc + r) * 145 + nt * 16 + l16] =
                            fmaxf(acc[mt][nt][r] + bia, 0.0f);
                }
            }
        }
        __syncthreads();
        #pragma unroll
        for (int i = 0; i < 2; ++i) {
            int comb = wave + 4 * i;      // 0..7 -> (ho_l, c_l)
            int ho_l = comb >> 2, c_l = comb & 3;
            int row_g = row_base + h * 2 + ho_l;
            int ho = row_g & 63;
            int c_g = nb * 4 + c_l;
            int wo = lane;

            float p[9];
            const float* xc = x + (size_t)(b * Cch + c_g) * WIMG * WIMG;
            #pragma unroll
            for (int qi = 0; qi < 3; ++qi) {
                int r = 2 * ho - 1 + qi;
                #pragma unroll
                for (int qj = 0; qj < 3; ++qj) {
                    int col = 2 * wo - 1 + qj;
                    float v = 0.0f;
                    if (r >= 0 && r < WIMG && col >= 0 && col < WIMG)
                        v = xc[r * WIMG + col];
                    p[qi * 3 + qj] = v;
                }
            }
            const float* yrow = y + (ho_l * 64 + wo) * 145 + c_l * 36;
            float o00 = 0.f, o01 = 0.f, o10 = 0.f, o11 = 0.f;
            #pragma unroll
            for (int q = 0; q < 9; ++q) {
                float pq = p[q];
                o00 = fmaf(pq, yrow[q * 4 + 0], o00);
                o01 = fmaf(pq, yrow[q * 4 + 1], o01);
                o10 = fmaf(pq, yrow[q * 4 + 2], o10);
                o11 = fmaf(pq, yrow[q * 4 + 3], o11);
            }
            size_t obase = (((size_t)(b * Cch + c_g) * WIMG) + 2 * ho) * WIMG + 2 * wo;
            *(float2*)(out + obase)        = make_float2(o00 * s9, o01 * s9);
            *(float2*)(out + obase + WIMG) = make_float2(o10 * s9, o11 * s9);
        }
    }
}

extern "C" void kernel_launch(void* const* d_in, const int* in_sizes, int n_in,
                              void* d_out, int out_size, void* d_ws, size_t ws_size,
                              hipStream_t stream) {
    const float* x      = (const float*)d_in[0];
    const float* conv_w = (const float*)d_in[1];
    const float* gamma  = (const float*)d_in[2];
    const float* beta   = (const float*)d_in[3];
    const float* mean   = (const float*)d_in[4];
    const float* var    = (const float*)d_in[5];
    float* out = (float*)d_out;

    __bf16* Wt    = (__bf16*)d_ws;
    float*  biasp = (float*)((char*)d_ws + BIAS_OFF);
    __bf16* feat  = (__bf16*)((char*)d_ws + FEAT_OFF);

    const int nPrep = OUTCH * KP + OUTCH;
    prep_kernel<<<(nPrep + 255) / 256, 256, 0, stream>>>(conv_w, gamma, beta,
                                                         mean, var, Wt, biasp);
    feat_kernel<<<Bsz * OH, 256, 0, stream>>>(x, feat);
    gemm_kernel<<<(MTOT / 256) * (OUTCH / 144), 256, 0, stream>>>(feat, Wt, biasp, x, out);
}

// Round 3
// 148.465 us; speedup vs baseline: 6.7257x; 1.4331x over previous
//
#include <hip/hip_runtime.h>
#include <math.h>

typedef __bf16 v8bf __attribute__((ext_vector_type(8)));
typedef float  v4f  __attribute__((ext_vector_type(4)));

constexpr int Bsz  = 8;
constexpr int Cch  = 32;
constexpr int WIMG = 128;
constexpr int OH   = 64;
constexpr int OW   = 64;
constexpr int INCH = 201;
constexpr int KP   = 224;
constexpr int NK   = 7;
constexpr int OUTCH = 1152;
constexpr int MTOT = Bsz * OH * OW;   // 32768
constexpr float BN_EPS = 1e-5f;

// ws layout
constexpr size_t WT_BYTES = (size_t)NK * OUTCH * 32 * 2;   // 516,096
constexpr size_t BIAS_OFF = WT_BYTES;
constexpr size_t FEAT_OFF = BIAS_OFF + OUTCH * 4;          // 520,704 (16-aligned)

// ---- async global->LDS (wave-uniform base + lane*16 contiguous) ----
typedef const void __attribute__((address_space(1)))* gas_ptr;
typedef void __attribute__((address_space(3)))* las_ptr;
__device__ __forceinline__ void load16_lds(const void* g, void* l) {
    __builtin_amdgcn_global_load_lds((gas_ptr)(uintptr_t)g, (las_ptr)(uintptr_t)l, 16, 0, 0);
}

// ---------------------------------------------------------------------------
// prep: BN-fold, bf16, transpose, k-tile: Wt [7][1152][32]
// ---------------------------------------------------------------------------
__global__ void prep_kernel(const float* __restrict__ conv_w,
                            const float* __restrict__ gamma,
                            const float* __restrict__ beta,
                            const float* __restrict__ mean,
                            const float* __restrict__ var,
                            __bf16* __restrict__ Wt,
                            float* __restrict__ biasp) {
    int idx = blockIdx.x * blockDim.x + threadIdx.x;
    const int nW = OUTCH * KP;
    if (idx < nW) {
        int o = idx / KP;
        int f = idx - o * KP;
        float inv = gamma[o] * rsqrtf(var[o] + BN_EPS);
        float v = (f < INCH) ? conv_w[o * INCH + f] * inv : 0.0f;
        Wt[((size_t)(f >> 5) * OUTCH + o) * 32 + (f & 31)] = (__bf16)v;
    } else if (idx < nW + OUTCH) {
        int o = idx - nW;
        float inv = gamma[o] * rsqrtf(var[o] + BN_EPS);
        biasp[o] = beta[o] - mean[o] * inv;
    }
}

// ---------------------------------------------------------------------------
// feat v2: one block per (b,ho). Vectorized feature build.
//  sx[c][i][132] fp32, p = col+1 (p=0 is left-pad zero).
//  cmax pass: 99 items, 32x float4 max  -> x1 reads are 1 scalar each.
//  x2/x3: thread (wp,g): float4 windows, 12 b128 + 12 b32 reads total.
//  sfeat [7][64 wo][32] bf16 in LDS -> 1 float4/thread/chunk copy-out.
// ---------------------------------------------------------------------------
constexpr int SXS = 132;   // padded sx row stride (floats), 528 B (16-aligned)
__global__ __launch_bounds__(256)
void feat_kernel(const float* __restrict__ x, __bf16* __restrict__ feat) {
    __shared__ __align__(16) float sx[Cch * 3 * SXS];     // 50,688 B
    __shared__ __align__(16) float cmax[3 * SXS];         //  1,584 B
    __shared__ __align__(16) __bf16 sfeat[NK * OW * 32];  // 28,672 B

    const int b  = blockIdx.x >> 6;
    const int ho = blockIdx.x & 63;
    const int t  = threadIdx.x;

    // stage 1: x rows 2ho-1..2ho+1, all 32 ch
    for (int idx = t; idx < Cch * 3 * 128; idx += 256) {
        int c   = idx / 384;
        int rem = idx - c * 384;
        int i   = rem >> 7;
        int col = rem & 127;
        int r   = 2 * ho - 1 + i;
        float v = 0.0f;
        if (r >= 0 && r < WIMG)
            v = x[(((size_t)(b * Cch + c) * WIMG) + r) * WIMG + col];
        sx[(c * 3 + i) * SXS + col + 1] = v;
    }
    if (t < 96) {   // zero pads: p=0 (col -1) and p=129..131
        float* row = sx + t * SXS;
        row[0] = 0.0f; row[129] = 0.0f; row[130] = 0.0f; row[131] = 0.0f;
    }
    __syncthreads();

    // cmax: column max over 32 channels (for x1). 99 items = 3 i x 33 quads.
    if (t < 99) {
        int i = t / 33, cg = t - i * 33;
        const float4* base = (const float4*)sx + i * (SXS / 4) + cg;
        float4 m = base[0];
        #pragma unroll 4
        for (int c = 1; c < Cch; ++c) {
            float4 v = base[(size_t)c * (3 * SXS / 4)];
            m.x = fmaxf(m.x, v.x); m.y = fmaxf(m.y, v.y);
            m.z = fmaxf(m.z, v.z); m.w = fmaxf(m.w, v.w);
        }
        ((float4*)cmax)[i * (SXS / 4) + cg] = m;
    }
    __syncthreads();

    // x1 features: f = i*3+j (9), value = cmax[i][2wo+j]
    for (int idx = t; idx < 9 * 64; idx += 256) {
        int f = idx >> 6, wo = idx & 63;
        int i = f / 3, j = f - 3 * i;
        sfeat[wo * 32 + f] = (__bf16)cmax[i * SXS + 2 * wo + j];
    }
    // x2/x3: thread = (wp 0..31, g 0..7); wo0=2wp, wo1=2wp+1; c = 4g..4g+3
    {
        const int wp = t & 31, g = t >> 5;
        const int wo0 = 2 * wp;
        #pragma unroll
        for (int cl = 0; cl < 4; ++cl) {
            int c = g * 4 + cl;
            float v[3][5];
            #pragma unroll
            for (int i = 0; i < 3; ++i) {
                const float* row = sx + (c * 3 + i) * SXS + 4 * wp;
                float4 q = *(const float4*)row;      // p = 4wp..4wp+3
                v[i][0] = q.x; v[i][1] = q.y; v[i][2] = q.z; v[i][3] = q.w;
                v[i][4] = row[4];                    // p = 4wp+4
            }
            #pragma unroll
            for (int i = 0; i < 3; ++i) {            // x3: f = 105 + c*3 + i
                int f = 105 + c * 3 + i;
                float a0 = fmaxf(fmaxf(v[i][0], v[i][1]), v[i][2]);
                float a1 = fmaxf(fmaxf(v[i][2], v[i][3]), v[i][4]);
                sfeat[(f >> 5) * 2048 + wo0 * 32 + (f & 31)]       = (__bf16)a0;
                sfeat[(f >> 5) * 2048 + (wo0 + 1) * 32 + (f & 31)] = (__bf16)a1;
            }
            #pragma unroll
            for (int j = 0; j < 3; ++j) {            // x2: f = 9 + c*3 + j
                int f = 9 + c * 3 + j;
                float a0 = fmaxf(fmaxf(v[0][j], v[1][j]), v[2][j]);
                float a1 = fmaxf(fmaxf(v[0][j + 2], v[1][j + 2]), v[2][j + 2]);
                sfeat[(f >> 5) * 2048 + wo0 * 32 + (f & 31)]       = (__bf16)a0;
                sfeat[(f >> 5) * 2048 + (wo0 + 1) * 32 + (f & 31)] = (__bf16)a1;
            }
        }
    }
    // zero K-padding features f = 201..223
    for (int idx = t; idx < 64 * 23; idx += 256) {
        int wo = idx / 23, fo = idx - wo * 23;
        int f = 201 + fo;
        sfeat[6 * 2048 + wo * 32 + (f & 31)] = (__bf16)0.0f;
    }
    __syncthreads();

    // copy-out: per kc chunk 4096 B = 256 float4, one per thread, coalesced
    const size_t spat0 = (size_t)(b * OH + ho) * OW;
    #pragma unroll
    for (int kc = 0; kc < NK; ++kc) {
        float4 vv = ((const float4*)sfeat)[kc * 256 + t];
        ((float4*)((char*)feat + ((size_t)kc * MTOT + spat0) * 64))[t] = vv;
    }
}

// ---------------------------------------------------------------------------
// gemm: MFMA bf16 16x16x32, block 256 thr, tile M=256 x N=144, K dbuf via
// global_load_lds (no VGPR staging -> no spills). 64 B rows (no padding):
// b128 frag reads hit 8 lanes per 16B-bank-group = conflict-free floor.
// Epilogue: 64-row y chunks (stride 156), fused bias/ReLU/dyn-kernel mean.
// ---------------------------------------------------------------------------
constexpr int YSTR = 156;   // y row stride (floats): 624 B, 16-aligned, quad-spread
__global__ __launch_bounds__(256, 2)
void gemm_kernel(const __bf16* __restrict__ feat,
                 const __bf16* __restrict__ Wt,
                 const float* __restrict__ biasp,
                 const float* __restrict__ x,
                 float* __restrict__ out) {
    __shared__ __align__(16) unsigned char lds[51200];
    // A dbuf @0 (2 x 16,384), B dbuf @32,768 (2 x 9,216); epilogue y @0 (39,936)

    const int t    = threadIdx.x;
    const int mb   = (int)blockIdx.x >> 3;
    const int nb   = (int)blockIdx.x & 7;
    const int M0   = mb * 256;
    const int N0   = nb * 144;
    const int wave = t >> 6, lane = t & 63, quad = lane >> 4, l16 = lane & 15;

    auto issue = [&](int ks, int buf) {
        const char* Ag = (const char*)feat + ((size_t)ks * MTOT + M0) * 64;
        char* Ab = (char*)lds + buf * 16384;
        #pragma unroll
        for (int i = 0; i < 4; ++i) {
            int off = (wave * 4 + i) * 1024 + lane * 16;
            load16_lds(Ag + off, Ab + off);
        }
        const char* Bg = (const char*)Wt + ((size_t)ks * OUTCH + N0) * 64;
        char* Bb = (char*)lds + 32768 + buf * 9216;
        int off0 = wave * 1024 + lane * 16;
        load16_lds(Bg + off0, Bb + off0);
        int off1 = off0 + 4096;
        load16_lds(Bg + off1, Bb + off1);
        if (wave == 0) {
            int off2 = 8192 + lane * 16;
            load16_lds(Bg + off2, Bb + off2);
        }
    };

    v4f acc[4][9];
    #pragma unroll
    for (int mt = 0; mt < 4; ++mt)
        #pragma unroll
        for (int nt = 0; nt < 9; ++nt)
            acc[mt][nt] = (v4f){0.f, 0.f, 0.f, 0.f};

    issue(0, 0);
    __syncthreads();

    for (int ks = 0; ks < NK; ++ks) {
        const int cur = ks & 1;
        if (ks + 1 < NK) issue(ks + 1, cur ^ 1);   // in flight across MFMA section

        const char* Ab = (const char*)lds + cur * 16384;
        const char* Bb = (const char*)lds + 32768 + cur * 9216;
        v8bf af[4];
        #pragma unroll
        for (int mt = 0; mt < 4; ++mt)
            af[mt] = *(const v8bf*)(Ab + (wave * 64 + mt * 16 + l16) * 64 + quad * 16);
        #pragma unroll
        for (int nt = 0; nt < 9; ++nt) {
            v8bf bf = *(const v8bf*)(Bb + (nt * 16 + l16) * 64 + quad * 16);
            #pragma unroll
            for (int mt = 0; mt < 4; ++mt)
                acc[mt][nt] = __builtin_amdgcn_mfma_f32_16x16x32_bf16(
                    af[mt], bf, acc[mt][nt], 0, 0, 0);
        }
        __syncthreads();   // drains global_load_lds (vmcnt) + guards dbuf reuse
    }

    // ---- epilogue ----
    float bia[9];
    #pragma unroll
    for (int nt = 0; nt < 9; ++nt) bia[nt] = biasp[N0 + nt * 16 + l16];

    float* y = (float*)lds;                 // [64][YSTR]
    const float s9 = 1.0f / 9.0f;

    for (int h = 0; h < 4; ++h) {
        __syncthreads();                    // prev chunk consumed / k-loop done
        if (wave == h) {
            #pragma unroll
            for (int mt = 0; mt < 4; ++mt)
                #pragma unroll
                for (int nt = 0; nt < 9; ++nt)
                    #pragma unroll
                    for (int r = 0; r < 4; ++r)
                        y[(mt * 16 + quad * 4 + r) * YSTR + nt * 16 + l16] =
                            fmaxf(acc[mt][nt][r] + bia[nt], 0.0f);
        }
        __syncthreads();

        const int m_base = M0 + h * 64;     // multiple of 64
        const int bb  = m_base >> 12;
        const int hob = (m_base >> 6) & 63;
        const int wo  = t >> 2;
        const int cl  = t & 3;
        const int cg  = nb * 4 + cl;

        float p[9];
        const float* xc = x + (size_t)(bb * Cch + cg) * WIMG * WIMG;
        #pragma unroll
        for (int qi = 0; qi < 3; ++qi) {
            int r = 2 * hob - 1 + qi;
            #pragma unroll
            for (int qj = 0; qj < 3; ++qj) {
                int col = 2 * wo - 1 + qj;
                float v = 0.0f;
                if (r >= 0 && r < WIMG && col >= 0 && col < WIMG)
                    v = xc[r * WIMG + col];
                p[qi * 3 + qj] = v;
            }
        }
        const float4* yrow = (const float4*)(y + wo * YSTR + cl * 36);
        float o00 = 0.f, o01 = 0.f, o10 = 0.f, o11 = 0.f;
        #pragma unroll
        for (int q = 0; q < 9; ++q) {
            float4 yv = yrow[q];
            float pq = p[q];
            o00 = fmaf(pq, yv.x, o00);
            o01 = fmaf(pq, yv.y, o01);
            o10 = fmaf(pq, yv.z, o10);
            o11 = fmaf(pq, yv.w, o11);
        }
        size_t obase = (((size_t)(bb * Cch + cg) * WIMG) + 2 * hob) * WIMG + 2 * wo;
        *(float2*)(out + obase)        = make_float2(o00 * s9, o01 * s9);
        *(float2*)(out + obase + WIMG) = make_float2(o10 * s9, o11 * s9);
    }
}

extern "C" void kernel_launch(void* const* d_in, const int* in_sizes, int n_in,
                              void* d_out, int out_size, void* d_ws, size_t ws_size,
                              hipStream_t stream) {
    const float* x      = (const float*)d_in[0];
    const float* conv_w = (const float*)d_in[1];
    const float* gamma  = (const float*)d_in[2];
    const float* beta   = (const float*)d_in[3];
    const float* mean   = (const float*)d_in[4];
    const float* var    = (const float*)d_in[5];
    float* out = (float*)d_out;

    __bf16* Wt    = (__bf16*)d_ws;
    float*  biasp = (float*)((char*)d_ws + BIAS_OFF);
    __bf16* feat  = (__bf16*)((char*)d_ws + FEAT_OFF);

    const int nPrep = OUTCH * KP + OUTCH;
    prep_kernel<<<(nPrep + 255) / 256, 256, 0, stream>>>(conv_w, gamma, beta,
                                                         mean, var, Wt, biasp);
    feat_kernel<<<Bsz * OH, 256, 0, stream>>>(x, feat);
    gemm_kernel<<<(MTOT / 256) * (OUTCH / 144), 256, 0, stream>>>(feat, Wt, biasp, x, out);
}

// Round 4
// 133.110 us; speedup vs baseline: 7.5016x; 1.1154x over previous
//
#include <hip/hip_runtime.h>
#include <math.h>

typedef __bf16 v8bf __attribute__((ext_vector_type(8)));
typedef float  v4f  __attribute__((ext_vector_type(4)));

constexpr int Bsz  = 8;
constexpr int Cch  = 32;
constexpr int WIMG = 128;
constexpr int OH   = 64;
constexpr int OW   = 64;
constexpr int INCH = 201;
constexpr int KP   = 224;
constexpr int NK   = 7;
constexpr int OUTCH = 1152;
constexpr int MTOT = Bsz * OH * OW;   // 32768
constexpr float BN_EPS = 1e-5f;

// ws layout
constexpr size_t WT_BYTES = (size_t)NK * OUTCH * 32 * 2;   // 516,096
constexpr size_t BIAS_OFF = WT_BYTES;
constexpr size_t FEAT_OFF = BIAS_OFF + OUTCH * 4;          // 520,704 (16-aligned)

// ---- async global->LDS (wave-uniform base + lane*16 contiguous) ----
typedef const void __attribute__((address_space(1)))* gas_ptr;
typedef void __attribute__((address_space(3)))* las_ptr;
__device__ __forceinline__ void load16_lds(const void* g, void* l) {
    __builtin_amdgcn_global_load_lds((gas_ptr)(uintptr_t)g, (las_ptr)(uintptr_t)l, 16, 0, 0);
}

// ---------------------------------------------------------------------------
// K1: fused prep (blocks >= 512) + feat (blocks 0..511).
//  prep: BN-fold, bf16, transpose, k-tile: Wt [7][1152][32] + bias.
//  feat: one block per (b,ho); vectorized feature build (Round-2-validated).
// ---------------------------------------------------------------------------
constexpr int SXS = 132;            // padded sx row stride (floats)
constexpr int FEAT_BLOCKS = Bsz * OH;        // 512
constexpr int NPREP = OUTCH * KP + OUTCH;    // 259,200
constexpr int PREP_BLOCKS = (NPREP + 255) / 256;

__global__ __launch_bounds__(256)
void prep_feat_kernel(const float* __restrict__ x,
                      const float* __restrict__ conv_w,
                      const float* __restrict__ gamma,
                      const float* __restrict__ beta,
                      const float* __restrict__ mean,
                      const float* __restrict__ var,
                      __bf16* __restrict__ Wt,
                      float* __restrict__ biasp,
                      __bf16* __restrict__ feat) {
    __shared__ __align__(16) float sx[Cch * 3 * SXS];     // 50,688 B
    __shared__ __align__(16) float cmax[3 * SXS];         //  1,584 B
    __shared__ __align__(16) __bf16 sfeat[NK * OW * 32];  // 28,672 B

    const int t = threadIdx.x;

    if (blockIdx.x >= FEAT_BLOCKS) {
        // ---- prep part ----
        int idx = ((int)blockIdx.x - FEAT_BLOCKS) * 256 + t;
        const int nW = OUTCH * KP;
        if (idx < nW) {
            int o = idx / KP;
            int f = idx - o * KP;
            float inv = gamma[o] * rsqrtf(var[o] + BN_EPS);
            float v = (f < INCH) ? conv_w[o * INCH + f] * inv : 0.0f;
            Wt[((size_t)(f >> 5) * OUTCH + o) * 32 + (f & 31)] = (__bf16)v;
        } else if (idx < nW + OUTCH) {
            int o = idx - nW;
            float inv = gamma[o] * rsqrtf(var[o] + BN_EPS);
            biasp[o] = beta[o] - mean[o] * inv;
        }
        return;
    }

    // ---- feat part ----
    const int b  = blockIdx.x >> 6;
    const int ho = blockIdx.x & 63;

    for (int idx = t; idx < Cch * 3 * 128; idx += 256) {
        int c   = idx / 384;
        int rem = idx - c * 384;
        int i   = rem >> 7;
        int col = rem & 127;
        int r   = 2 * ho - 1 + i;
        float v = 0.0f;
        if (r >= 0 && r < WIMG)
            v = x[(((size_t)(b * Cch + c) * WIMG) + r) * WIMG + col];
        sx[(c * 3 + i) * SXS + col + 1] = v;
    }
    if (t < 96) {
        float* row = sx + t * SXS;
        row[0] = 0.0f; row[129] = 0.0f; row[130] = 0.0f; row[131] = 0.0f;
    }
    __syncthreads();

    if (t < 99) {     // column max over 32 channels (x1 source)
        int i = t / 33, cg = t - i * 33;
        const float4* base = (const float4*)sx + i * (SXS / 4) + cg;
        float4 m = base[0];
        #pragma unroll 4
        for (int c = 1; c < Cch; ++c) {
            float4 v = base[(size_t)c * (3 * SXS / 4)];
            m.x = fmaxf(m.x, v.x); m.y = fmaxf(m.y, v.y);
            m.z = fmaxf(m.z, v.z); m.w = fmaxf(m.w, v.w);
        }
        ((float4*)cmax)[i * (SXS / 4) + cg] = m;
    }
    __syncthreads();

    for (int idx = t; idx < 9 * 64; idx += 256) {     // x1
        int f = idx >> 6, wo = idx & 63;
        int i = f / 3, j = f - 3 * i;
        sfeat[wo * 32 + f] = (__bf16)cmax[i * SXS + 2 * wo + j];
    }
    {   // x2/x3
        const int wp = t & 31, g = t >> 5;
        const int wo0 = 2 * wp;
        #pragma unroll
        for (int cl = 0; cl < 4; ++cl) {
            int c = g * 4 + cl;
            float v[3][5];
            #pragma unroll
            for (int i = 0; i < 3; ++i) {
                const float* row = sx + (c * 3 + i) * SXS + 4 * wp;
                float4 q = *(const float4*)row;
                v[i][0] = q.x; v[i][1] = q.y; v[i][2] = q.z; v[i][3] = q.w;
                v[i][4] = row[4];
            }
            #pragma unroll
            for (int i = 0; i < 3; ++i) {            // x3
                int f = 105 + c * 3 + i;
                float a0 = fmaxf(fmaxf(v[i][0], v[i][1]), v[i][2]);
                float a1 = fmaxf(fmaxf(v[i][2], v[i][3]), v[i][4]);
                sfeat[(f >> 5) * 2048 + wo0 * 32 + (f & 31)]       = (__bf16)a0;
                sfeat[(f >> 5) * 2048 + (wo0 + 1) * 32 + (f & 31)] = (__bf16)a1;
            }
            #pragma unroll
            for (int j = 0; j < 3; ++j) {            // x2
                int f = 9 + c * 3 + j;
                float a0 = fmaxf(fmaxf(v[0][j], v[1][j]), v[2][j]);
                float a1 = fmaxf(fmaxf(v[0][j + 2], v[1][j + 2]), v[2][j + 2]);
                sfeat[(f >> 5) * 2048 + wo0 * 32 + (f & 31)]       = (__bf16)a0;
                sfeat[(f >> 5) * 2048 + (wo0 + 1) * 32 + (f & 31)] = (__bf16)a1;
            }
        }
    }
    for (int idx = t; idx < 64 * 23; idx += 256) {   // K padding
        int wo = idx / 23, fo = idx - wo * 23;
        int f = 201 + fo;
        sfeat[6 * 2048 + wo * 32 + (f & 31)] = (__bf16)0.0f;
    }
    __syncthreads();

    const size_t spat0 = (size_t)(b * OH + ho) * OW;
    #pragma unroll
    for (int kc = 0; kc < NK; ++kc) {
        float4 vv = ((const float4*)sfeat)[kc * 256 + t];
        ((float4*)((char*)feat + ((size_t)kc * MTOT + spat0) * 64))[t] = vv;
    }
}

// ---------------------------------------------------------------------------
// K2: gemm. MFMA bf16 16x16x32, block 256 thr, tile M=256 x N=144, K dbuf via
// global_load_lds. blockIdx = nb*128 + mb: the 8 nb-blocks of one mb land on
// one XCD (round-robin %8) -> A tile L2-resident, FETCH ~= unique bytes.
// Epilogue: barrier-free per-wave transpose through a private LDS region.
// ---------------------------------------------------------------------------
constexpr int YS  = 148;            // y row stride (floats)
constexpr int REG = 16 * YS;        // per-wave y region (floats) = 9,472 B
__global__ __launch_bounds__(256, 2)
void gemm_kernel(const __bf16* __restrict__ feat,
                 const __bf16* __restrict__ Wt,
                 const float* __restrict__ biasp,
                 const float* __restrict__ x,
                 float* __restrict__ out) {
    __shared__ __align__(16) unsigned char lds[51200];
    // A dbuf @0 (2x16,384), B dbuf @32,768 (2x9,216); epilogue y @0 (4x9,472)

    const int t    = threadIdx.x;
    const int nb   = (int)blockIdx.x >> 7;   // 0..7
    const int mb   = (int)blockIdx.x & 127;  // 0..127
    const int M0   = mb * 256;
    const int N0   = nb * 144;
    const int wave = t >> 6, lane = t & 63, quad = lane >> 4, l16 = lane & 15;

    auto issue = [&](int ks, int buf) {
        const char* Ag = (const char*)feat + ((size_t)ks * MTOT + M0) * 64;
        char* Ab = (char*)lds + buf * 16384;
        #pragma unroll
        for (int i = 0; i < 4; ++i) {
            int off = (wave * 4 + i) * 1024 + lane * 16;
            load16_lds(Ag + off, Ab + off);
        }
        const char* Bg = (const char*)Wt + ((size_t)ks * OUTCH + N0) * 64;
        char* Bb = (char*)lds + 32768 + buf * 9216;
        int off0 = wave * 1024 + lane * 16;
        load16_lds(Bg + off0, Bb + off0);
        int off1 = off0 + 4096;
        load16_lds(Bg + off1, Bb + off1);
        if (wave == 0) {
            int off2 = 8192 + lane * 16;
            load16_lds(Bg + off2, Bb + off2);
        }
    };

    v4f acc[4][9];
    #pragma unroll
    for (int mt = 0; mt < 4; ++mt)
        #pragma unroll
        for (int nt = 0; nt < 9; ++nt)
            acc[mt][nt] = (v4f){0.f, 0.f, 0.f, 0.f};

    issue(0, 0);
    __syncthreads();

    for (int ks = 0; ks < NK; ++ks) {
        const int cur = ks & 1;
        if (ks + 1 < NK) issue(ks + 1, cur ^ 1);

        const char* Ab = (const char*)lds + cur * 16384;
        const char* Bb = (const char*)lds + 32768 + cur * 9216;
        v8bf af[4];
        #pragma unroll
        for (int mt = 0; mt < 4; ++mt)
            af[mt] = *(const v8bf*)(Ab + (wave * 64 + mt * 16 + l16) * 64 + quad * 16);
        #pragma unroll
        for (int nt = 0; nt < 9; ++nt) {
            v8bf bf = *(const v8bf*)(Bb + (nt * 16 + l16) * 64 + quad * 16);
            #pragma unroll
            for (int mt = 0; mt < 4; ++mt)
                acc[mt][nt] = __builtin_amdgcn_mfma_f32_16x16x32_bf16(
                    af[mt], bf, acc[mt][nt], 0, 0, 0);
        }
        __syncthreads();   // drains global_load_lds + guards dbuf/epilogue reuse
    }

    // ---- epilogue: per-wave private transpose; no cross-wave barriers ----
    float bia[9];
    #pragma unroll
    for (int nt = 0; nt < 9; ++nt) bia[nt] = biasp[N0 + nt * 16 + l16];

    float* yw = (float*)lds + wave * REG;        // private [16][YS]
    const int bb  = M0 >> 12;
    const int hob = ((M0 >> 6) & 63) + wave;     // this wave's ho
    const int cl  = lane >> 4;                   // 0..3 channel-sub
    const int wl  = lane & 15;                   // wo within 16-block
    const int cg  = nb * 4 + cl;
    const float s9 = 1.0f / 9.0f;
    const float* xc = x + (size_t)(bb * Cch + cg) * WIMG * WIMG;

    #pragma unroll
    for (int p = 0; p < 4; ++p) {
        // produce: this wave's M-tile p (rows quad*4+r, cols nt*16+l16)
        #pragma unroll
        for (int nt = 0; nt < 9; ++nt)
            #pragma unroll
            for (int r = 0; r < 4; ++r)
                yw[(quad * 4 + r) * YS + nt * 16 + l16] =
                    fmaxf(acc[p][nt][r] + bia[nt], 0.0f);

        // consume: lane -> (wo = p*16+wl, channel cg), read own region
        const int wo = p * 16 + wl;
        float pt[9];
        #pragma unroll
        for (int qi = 0; qi < 3; ++qi) {
            int r = 2 * hob - 1 + qi;
            #pragma unroll
            for (int qj = 0; qj < 3; ++qj) {
                int col = 2 * wo - 1 + qj;
                float v = 0.0f;
                if (r >= 0 && r < WIMG && col >= 0 && col < WIMG)
                    v = xc[r * WIMG + col];
                pt[qi * 3 + qj] = v;
            }
        }
        const float4* yrow = (const float4*)(yw + wl * YS + cl * 36);
        float o00 = 0.f, o01 = 0.f, o10 = 0.f, o11 = 0.f;
        #pragma unroll
        for (int q = 0; q < 9; ++q) {
            float4 yv = yrow[q];
            float pq = pt[q];
            o00 = fmaf(pq, yv.x, o00);
            o01 = fmaf(pq, yv.y, o01);
            o10 = fmaf(pq, yv.z, o10);
            o11 = fmaf(pq, yv.w, o11);
        }
        size_t obase = (((size_t)(bb * Cch + cg) * WIMG) + 2 * hob) * WIMG + 2 * wo;
        *(float2*)(out + obase)        = make_float2(o00 * s9, o01 * s9);
        *(float2*)(out + obase + WIMG) = make_float2(o10 * s9, o11 * s9);
    }
}

extern "C" void kernel_launch(void* const* d_in, const int* in_sizes, int n_in,
                              void* d_out, int out_size, void* d_ws, size_t ws_size,
                              hipStream_t stream) {
    const float* x      = (const float*)d_in[0];
    const float* conv_w = (const float*)d_in[1];
    const float* gamma  = (const float*)d_in[2];
    const float* beta   = (const float*)d_in[3];
    const float* mean   = (const float*)d_in[4];
    const float* var    = (const float*)d_in[5];
    float* out = (float*)d_out;

    __bf16* Wt    = (__bf16*)d_ws;
    float*  biasp = (float*)((char*)d_ws + BIAS_OFF);
    __bf16* feat  = (__bf16*)((char*)d_ws + FEAT_OFF);

    prep_feat_kernel<<<FEAT_BLOCKS + PREP_BLOCKS, 256, 0, stream>>>(
        x, conv_w, gamma, beta, mean, var, Wt, biasp, feat);
    gemm_kernel<<<(OUTCH / 144) * (MTOT / 256), 256, 0, stream>>>(feat, Wt, biasp, x, out);
}

// Round 5
// 118.368 us; speedup vs baseline: 8.4358x; 1.1245x over previous
//
#include <hip/hip_runtime.h>
#include <math.h>

typedef __bf16 v8bf __attribute__((ext_vector_type(8)));
typedef float  v4f  __attribute__((ext_vector_type(4)));

constexpr int Bsz  = 8;
constexpr int Cch  = 32;
constexpr int WIMG = 128;
constexpr int OH   = 64;
constexpr int OW   = 64;
constexpr int INCH = 201;
constexpr int KP   = 224;
constexpr int NK   = 7;
constexpr int OUTCH = 1152;
constexpr int MTOT = Bsz * OH * OW;   // 32768
constexpr float BN_EPS = 1e-5f;

// ws layout
constexpr size_t WT_BYTES = (size_t)NK * OUTCH * 32 * 2;   // 516,096
constexpr size_t BIAS_OFF = WT_BYTES;
constexpr size_t FEAT_OFF = BIAS_OFF + OUTCH * 4;          // 520,704 (16-aligned)

// ---- async global->LDS (wave-uniform base + lane*16 contiguous) ----
typedef const void __attribute__((address_space(1)))* gas_ptr;
typedef void __attribute__((address_space(3)))* las_ptr;
__device__ __forceinline__ void load16_lds(const void* g, void* l) {
    __builtin_amdgcn_global_load_lds((gas_ptr)(uintptr_t)g, (las_ptr)(uintptr_t)l, 16, 0, 0);
}

// ---------------------------------------------------------------------------
// K1: fused prep (blocks >= 512) + feat (blocks 0..511).
// ---------------------------------------------------------------------------
constexpr int SXS = 132;            // padded sx row stride (floats)
constexpr int FEAT_BLOCKS = Bsz * OH;        // 512
constexpr int NPREP = OUTCH * KP + OUTCH;    // 259,200
constexpr int PREP_BLOCKS = (NPREP + 255) / 256;

__global__ __launch_bounds__(256)
void prep_feat_kernel(const float* __restrict__ x,
                      const float* __restrict__ conv_w,
                      const float* __restrict__ gamma,
                      const float* __restrict__ beta,
                      const float* __restrict__ mean,
                      const float* __restrict__ var,
                      __bf16* __restrict__ Wt,
                      float* __restrict__ biasp,
                      __bf16* __restrict__ feat) {
    __shared__ __align__(16) float sx[Cch * 3 * SXS];     // 50,688 B
    __shared__ __align__(16) float cmax[3 * SXS];         //  1,584 B
    __shared__ __align__(16) __bf16 sfeat[NK * OW * 32];  // 28,672 B

    const int t = threadIdx.x;

    if (blockIdx.x >= FEAT_BLOCKS) {
        // ---- prep part ----
        int idx = ((int)blockIdx.x - FEAT_BLOCKS) * 256 + t;
        const int nW = OUTCH * KP;
        if (idx < nW) {
            int o = idx / KP;
            int f = idx - o * KP;
            float inv = gamma[o] * rsqrtf(var[o] + BN_EPS);
            float v = (f < INCH) ? conv_w[o * INCH + f] * inv : 0.0f;
            Wt[((size_t)(f >> 5) * OUTCH + o) * 32 + (f & 31)] = (__bf16)v;
        } else if (idx < nW + OUTCH) {
            int o = idx - nW;
            float inv = gamma[o] * rsqrtf(var[o] + BN_EPS);
            biasp[o] = beta[o] - mean[o] * inv;
        }
        return;
    }

    // ---- feat part ----
    const int b  = blockIdx.x >> 6;
    const int ho = blockIdx.x & 63;

    // stage 1: float4 loads (12/thread), 3 rows x 32 ch
    for (int idx = t; idx < Cch * 3 * 32; idx += 256) {
        int c   = idx / 96;
        int rem = idx - c * 96;
        int i   = rem >> 5;
        int q   = rem & 31;
        int r   = 2 * ho - 1 + i;
        float4 v = make_float4(0.f, 0.f, 0.f, 0.f);
        if (r >= 0 && r < WIMG)
            v = *(const float4*)(x + (((size_t)(b * Cch + c) * WIMG) + r) * WIMG + q * 4);
        float* dst = sx + (c * 3 + i) * SXS + q * 4 + 1;
        dst[0] = v.x; dst[1] = v.y; dst[2] = v.z; dst[3] = v.w;
    }
    if (t < 96) {
        float* row = sx + t * SXS;
        row[0] = 0.0f; row[129] = 0.0f; row[130] = 0.0f; row[131] = 0.0f;
    }
    __syncthreads();

    if (t < 99) {     // column max over 32 channels (x1 source)
        int i = t / 33, cg = t - i * 33;
        const float4* base = (const float4*)sx + i * (SXS / 4) + cg;
        float4 m = base[0];
        #pragma unroll 4
        for (int c = 1; c < Cch; ++c) {
            float4 v = base[(size_t)c * (3 * SXS / 4)];
            m.x = fmaxf(m.x, v.x); m.y = fmaxf(m.y, v.y);
            m.z = fmaxf(m.z, v.z); m.w = fmaxf(m.w, v.w);
        }
        ((float4*)cmax)[i * (SXS / 4) + cg] = m;
    }
    __syncthreads();

    for (int idx = t; idx < 9 * 64; idx += 256) {     // x1
        int f = idx >> 6, wo = idx & 63;
        int i = f / 3, j = f - 3 * i;
        sfeat[wo * 32 + f] = (__bf16)cmax[i * SXS + 2 * wo + j];
    }
    {   // x2/x3
        const int wp = t & 31, g = t >> 5;
        const int wo0 = 2 * wp;
        #pragma unroll
        for (int cl = 0; cl < 4; ++cl) {
            int c = g * 4 + cl;
            float v[3][5];
            #pragma unroll
            for (int i = 0; i < 3; ++i) {
                const float* row = sx + (c * 3 + i) * SXS + 4 * wp;
                float4 q = *(const float4*)row;
                v[i][0] = q.x; v[i][1] = q.y; v[i][2] = q.z; v[i][3] = q.w;
                v[i][4] = row[4];
            }
            #pragma unroll
            for (int i = 0; i < 3; ++i) {            // x3
                int f = 105 + c * 3 + i;
                float a0 = fmaxf(fmaxf(v[i][0], v[i][1]), v[i][2]);
                float a1 = fmaxf(fmaxf(v[i][2], v[i][3]), v[i][4]);
                sfeat[(f >> 5) * 2048 + wo0 * 32 + (f & 31)]       = (__bf16)a0;
                sfeat[(f >> 5) * 2048 + (wo0 + 1) * 32 + (f & 31)] = (__bf16)a1;
            }
            #pragma unroll
            for (int j = 0; j < 3; ++j) {            // x2
                int f = 9 + c * 3 + j;
                float a0 = fmaxf(fmaxf(v[0][j], v[1][j]), v[2][j]);
                float a1 = fmaxf(fmaxf(v[0][j + 2], v[1][j + 2]), v[2][j + 2]);
                sfeat[(f >> 5) * 2048 + wo0 * 32 + (f & 31)]       = (__bf16)a0;
                sfeat[(f >> 5) * 2048 + (wo0 + 1) * 32 + (f & 31)] = (__bf16)a1;
            }
        }
    }
    for (int idx = t; idx < 64 * 23; idx += 256) {   // K padding
        int wo = idx / 23, fo = idx - wo * 23;
        int f = 201 + fo;
        sfeat[6 * 2048 + wo * 32 + (f & 31)] = (__bf16)0.0f;
    }
    __syncthreads();

    const size_t spat0 = (size_t)(b * OH + ho) * OW;
    #pragma unroll
    for (int kc = 0; kc < NK; ++kc) {
        float4 vv = ((const float4*)sfeat)[kc * 256 + t];
        ((float4*)((char*)feat + ((size_t)kc * MTOT + spat0) * 64))[t] = vv;
    }
}

// ---------------------------------------------------------------------------
// K2: gemm. MFMA bf16 16x16x32, block 256 thr, tile M=128 x N=144, K dbuf via
// global_load_lds. acc = 2x9 v4f (72 regs) -> ~145 total unified regs ->
// 3-4 waves/SIMD; LDS 37.9 KB -> 4 blocks/CU. blockIdx = nb*256 + mb keeps
// the 8 nb-blocks of one mb on one XCD (A L2-resident).
// Epilogue: barrier-free per-wave transpose through a private LDS region.
// ---------------------------------------------------------------------------
constexpr int YS  = 148;            // y row stride (floats)
constexpr int REG = 16 * YS;        // per-wave y region (floats) = 9,472 B
__global__ __launch_bounds__(256, 2)
void gemm_kernel(const __bf16* __restrict__ feat,
                 const __bf16* __restrict__ Wt,
                 const float* __restrict__ biasp,
                 const float* __restrict__ x,
                 float* __restrict__ out) {
    __shared__ __align__(16) unsigned char lds[37888];
    // A dbuf @0 (2x8,192), B dbuf @16,384 (2x9,216); epilogue y @0 (4x9,472)

    const int t    = threadIdx.x;
    const int nb   = (int)blockIdx.x >> 8;   // 0..7
    const int mb   = (int)blockIdx.x & 255;  // 0..255
    const int M0   = mb * 128;
    const int N0   = nb * 144;
    const int wave = t >> 6, lane = t & 63, quad = lane >> 4, l16 = lane & 15;

    auto issue = [&](int ks, int buf) {
        const char* Ag = (const char*)feat + ((size_t)ks * MTOT + M0) * 64;
        char* Ab = (char*)lds + buf * 8192;
        #pragma unroll
        for (int i = 0; i < 2; ++i) {
            int off = (wave * 2 + i) * 1024 + lane * 16;
            load16_lds(Ag + off, Ab + off);
        }
        const char* Bg = (const char*)Wt + ((size_t)ks * OUTCH + N0) * 64;
        char* Bb = (char*)lds + 16384 + buf * 9216;
        #pragma unroll
        for (int i = 0; i < 2; ++i) {
            int off = (wave * 2 + i) * 1024 + lane * 16;
            load16_lds(Bg + off, Bb + off);
        }
        if (wave == 0) {
            int off2 = 8192 + lane * 16;
            load16_lds(Bg + off2, Bb + off2);
        }
    };

    v4f acc[2][9];
    #pragma unroll
    for (int mt = 0; mt < 2; ++mt)
        #pragma unroll
        for (int nt = 0; nt < 9; ++nt)
            acc[mt][nt] = (v4f){0.f, 0.f, 0.f, 0.f};

    issue(0, 0);
    __syncthreads();

    for (int ks = 0; ks < NK; ++ks) {
        const int cur = ks & 1;
        if (ks + 1 < NK) issue(ks + 1, cur ^ 1);

        const char* Ab = (const char*)lds + cur * 8192;
        const char* Bb = (const char*)lds + 16384 + cur * 9216;
        v8bf af[2];
        #pragma unroll
        for (int mt = 0; mt < 2; ++mt)
            af[mt] = *(const v8bf*)(Ab + (wave * 32 + mt * 16 + l16) * 64 + quad * 16);
        #pragma unroll
        for (int nt = 0; nt < 9; ++nt) {
            v8bf bf = *(const v8bf*)(Bb + (nt * 16 + l16) * 64 + quad * 16);
            #pragma unroll
            for (int mt = 0; mt < 2; ++mt)
                acc[mt][nt] = __builtin_amdgcn_mfma_f32_16x16x32_bf16(
                    af[mt], bf, acc[mt][nt], 0, 0, 0);
        }
        __syncthreads();   // drains global_load_lds + guards dbuf/epilogue reuse
    }

    // ---- epilogue: per-wave private transpose; no cross-wave barriers ----
    float bia[9];
    #pragma unroll
    for (int nt = 0; nt < 9; ++nt) bia[nt] = biasp[N0 + nt * 16 + l16];

    float* yw = (float*)lds + wave * REG;        // private [16][YS]
    const int cl  = lane >> 4;                   // 0..3 channel-sub
    const int wl  = lane & 15;                   // wo within 16-block
    const int cg  = nb * 4 + cl;
    const float s9 = 1.0f / 9.0f;

    #pragma unroll
    for (int p = 0; p < 2; ++p) {
        // produce: this wave's M-tile p (rows quad*4+r, cols nt*16+l16)
        #pragma unroll
        for (int nt = 0; nt < 9; ++nt)
            #pragma unroll
            for (int r = 0; r < 4; ++r)
                yw[(quad * 4 + r) * YS + nt * 16 + l16] =
                    fmaxf(acc[p][nt][r] + bia[nt], 0.0f);

        // consume: lane -> global row M0 + wave*32 + p*16 + wl
        const int mg  = M0 + wave * 32 + p * 16 + wl;
        const int bb  = mg >> 12;
        const int hob = (mg >> 6) & 63;
        const int wo  = mg & 63;
        const float* xc = x + (size_t)(bb * Cch + cg) * WIMG * WIMG;

        float pt[9];
        #pragma unroll
        for (int qi = 0; qi < 3; ++qi) {
            int r = 2 * hob - 1 + qi;
            #pragma unroll
            for (int qj = 0; qj < 3; ++qj) {
                int col = 2 * wo - 1 + qj;
                float v = 0.0f;
                if (r >= 0 && r < WIMG && col >= 0 && col < WIMG)
                    v = xc[r * WIMG + col];
                pt[qi * 3 + qj] = v;
            }
        }
        const float4* yrow = (const float4*)(yw + wl * YS + cl * 36);
        float o00 = 0.f, o01 = 0.f, o10 = 0.f, o11 = 0.f;
        #pragma unroll
        for (int q = 0; q < 9; ++q) {
            float4 yv = yrow[q];
            float pq = pt[q];
            o00 = fmaf(pq, yv.x, o00);
            o01 = fmaf(pq, yv.y, o01);
            o10 = fmaf(pq, yv.z, o10);
            o11 = fmaf(pq, yv.w, o11);
        }
        size_t obase = (((size_t)(bb * Cch + cg) * WIMG) + 2 * hob) * WIMG + 2 * wo;
        *(float2*)(out + obase)        = make_float2(o00 * s9, o01 * s9);
        *(float2*)(out + obase + WIMG) = make_float2(o10 * s9, o11 * s9);
    }
}

extern "C" void kernel_launch(void* const* d_in, const int* in_sizes, int n_in,
                              void* d_out, int out_size, void* d_ws, size_t ws_size,
                              hipStream_t stream) {
    const float* x      = (const float*)d_in[0];
    const float* conv_w = (const float*)d_in[1];
    const float* gamma  = (const float*)d_in[2];
    const float* beta   = (const float*)d_in[3];
    const float* mean   = (const float*)d_in[4];
    const float* var    = (const float*)d_in[5];
    float* out = (float*)d_out;

    __bf16* Wt    = (__bf16*)d_ws;
    float*  biasp = (float*)((char*)d_ws + BIAS_OFF);
    __bf16* feat  = (__bf16*)((char*)d_ws + FEAT_OFF);

    prep_feat_kernel<<<FEAT_BLOCKS + PREP_BLOCKS, 256, 0, stream>>>(
        x, conv_w, gamma, beta, mean, var, Wt, biasp, feat);
    gemm_kernel<<<(OUTCH / 144) * (MTOT / 128), 256, 0, stream>>>(feat, Wt, biasp, x, out);
}